// Round 1
// baseline (1352.757 us; speedup 1.0000x reference)
//
#include <hip/hip_runtime.h>
#include <hip/hip_bf16.h>

#define N_NODES 100000

// ---------------------------------------------------------------- CSR build
__global__ void count_kernel(const int* __restrict__ dst, int E, int* __restrict__ cnt) {
    int i = blockIdx.x * 256 + threadIdx.x;
    if (i < E) atomicAdd(&cnt[dst[i]], 1);
}

// single block, 256 threads: exclusive prefix sum of cnt[0..n) -> row_off, cursor
__global__ void scan_kernel(const int* __restrict__ cnt, int* __restrict__ row_off,
                            int* __restrict__ cursor, int n) {
    __shared__ int sums[256];
    int tid = threadIdx.x;
    int per = (n + 255) / 256;
    int b = tid * per;
    int e = min(b + per, n);
    int s = 0;
    for (int i = b; i < e; ++i) s += cnt[i];
    sums[tid] = s;
    __syncthreads();
    for (int off = 1; off < 256; off <<= 1) {
        int v = 0;
        if (tid >= off) v = sums[tid - off];
        __syncthreads();
        if (tid >= off) sums[tid] += v;
        __syncthreads();
    }
    int run = (tid > 0) ? sums[tid - 1] : 0;
    for (int i = b; i < e; ++i) {
        int c = cnt[i];
        row_off[i] = run;
        cursor[i] = run;
        run += c;
    }
    if (tid == 255) row_off[n] = run;
}

__global__ void fill_kernel(const int* __restrict__ src, const int* __restrict__ dst, int E,
                            int* __restrict__ cursor, int* __restrict__ csr_src) {
    int i = blockIdx.x * 256 + threadIdx.x;
    if (i < E) {
        int d = dst[i];
        int p = atomicAdd(&cursor[d], 1);
        csr_src[p] = src[i];
    }
}

// ------------------------------------------------------- mean aggregation (F=128)
// one wave per dst node; lane handles float2 (features 2*lane, 2*lane+1)
__global__ __launch_bounds__(256) void agg_kernel(const float* __restrict__ feat,
                                                  const int* __restrict__ row_off,
                                                  const int* __restrict__ csr,
                                                  float* __restrict__ outf, int M) {
    int node = blockIdx.x * 4 + (threadIdx.x >> 6);
    if (node >= M) return;
    int lane = threadIdx.x & 63;
    int beg = row_off[node], end = row_off[node + 1];
    const float2* f2 = (const float2*)feat;
    float sx = 0.f, sy = 0.f;
    int i = beg;
    for (; i + 4 <= end; i += 4) {
        int s0 = csr[i], s1 = csr[i + 1], s2 = csr[i + 2], s3 = csr[i + 3];
        float2 v0 = f2[(size_t)s0 * 64 + lane];
        float2 v1 = f2[(size_t)s1 * 64 + lane];
        float2 v2 = f2[(size_t)s2 * 64 + lane];
        float2 v3 = f2[(size_t)s3 * 64 + lane];
        sx += v0.x + v1.x + v2.x + v3.x;
        sy += v0.y + v1.y + v2.y + v3.y;
    }
    for (; i < end; ++i) {
        int s = csr[i];
        float2 v = f2[(size_t)s * 64 + lane];
        sx += v.x;
        sy += v.y;
    }
    float inv = (end > beg) ? 1.0f / (float)(end - beg) : 0.0f;
    float2 o;
    o.x = sx * inv;
    o.y = sy * inv;
    ((float2*)outf)[(size_t)node * 64 + lane] = o;
}

// --------------------------------------------- fused dual GEMM: out = act(A1@W1^T + A2@W2^T + b)
// A1,A2: [M,128]; W1,W2: [128,128] row-major (out_j uses W[j][k]); out: [M,128]
#define BM 64
#define KB 32
__global__ __launch_bounds__(256) void gemm_dual(const float* __restrict__ A1,
                                                 const float* __restrict__ A2,
                                                 const float* __restrict__ W1,
                                                 const float* __restrict__ W2,
                                                 const float* __restrict__ bias,
                                                 float* __restrict__ out, int M, int relu) {
    __shared__ float As[KB][BM + 4];    // stride 68 floats (272 B, 16B-aligned)
    __shared__ float Ws[KB][128 + 4];   // stride 132 floats (528 B, 16B-aligned)
    int tid = threadIdx.x;
    int row0 = blockIdx.x * BM;
    int tr = tid >> 5;   // 0..7
    int tc = tid & 31;   // 0..31
    int r0 = tr * 8;
    int c0 = tc * 4;
    float acc[8][4];
#pragma unroll
    for (int i = 0; i < 8; ++i)
#pragma unroll
        for (int c = 0; c < 4; ++c) acc[i][c] = 0.f;

    for (int half = 0; half < 2; ++half) {
        const float* A = half ? A2 : A1;
        const float* W = half ? W2 : W1;
        for (int kc = 0; kc < 128; kc += KB) {
            // stage A tile 64x32 (transposed into As[k][m])
#pragma unroll
            for (int t = 0; t < 2; ++t) {
                int f = tid + t * 256;   // 0..511
                int r = f >> 3;          // 0..63
                int c4 = (f & 7) * 4;    // 0,4,..,28
                int gr = row0 + r;
                float4 v = make_float4(0.f, 0.f, 0.f, 0.f);
                if (gr < M) v = *(const float4*)&A[(size_t)gr * 128 + kc + c4];
                As[c4 + 0][r] = v.x;
                As[c4 + 1][r] = v.y;
                As[c4 + 2][r] = v.z;
                As[c4 + 3][r] = v.w;
            }
            // stage W tile 128x32 (transposed into Ws[k][j])
#pragma unroll
            for (int t = 0; t < 4; ++t) {
                int f = tid + t * 256;   // 0..1023
                int j = f >> 3;          // 0..127
                int c4 = (f & 7) * 4;
                float4 v = *(const float4*)&W[(size_t)j * 128 + kc + c4];
                Ws[c4 + 0][j] = v.x;
                Ws[c4 + 1][j] = v.y;
                Ws[c4 + 2][j] = v.z;
                Ws[c4 + 3][j] = v.w;
            }
            __syncthreads();
#pragma unroll
            for (int k = 0; k < KB; ++k) {
                float4 a0 = *(const float4*)&As[k][r0];
                float4 a1 = *(const float4*)&As[k][r0 + 4];
                float4 bv = *(const float4*)&Ws[k][c0];
                float av[8] = {a0.x, a0.y, a0.z, a0.w, a1.x, a1.y, a1.z, a1.w};
                float bb[4] = {bv.x, bv.y, bv.z, bv.w};
#pragma unroll
                for (int i = 0; i < 8; ++i)
#pragma unroll
                    for (int c = 0; c < 4; ++c) acc[i][c] += av[i] * bb[c];
            }
            __syncthreads();
        }
    }
    // epilogue
#pragma unroll
    for (int i = 0; i < 8; ++i) {
        int gr = row0 + r0 + i;
        if (gr < M) {
            float4 o;
            o.x = acc[i][0] + bias[c0 + 0];
            o.y = acc[i][1] + bias[c0 + 1];
            o.z = acc[i][2] + bias[c0 + 2];
            o.w = acc[i][3] + bias[c0 + 3];
            if (relu) {
                o.x = fmaxf(o.x, 0.f);
                o.y = fmaxf(o.y, 0.f);
                o.z = fmaxf(o.z, 0.f);
                o.w = fmaxf(o.w, 0.f);
            }
            *(float4*)&out[(size_t)gr * 128 + c0] = o;
        }
    }
}

// ------------------------------------- layer 3 transform: zr[n][0..5]=h@Wl3^T, [6..11]=h@Wr3^T+b3
__global__ __launch_bounds__(256) void lin3_kernel(const float* __restrict__ h,
                                                   const float* __restrict__ Wl,
                                                   const float* __restrict__ Wr,
                                                   const float* __restrict__ b3,
                                                   float* __restrict__ zr, int M) {
    __shared__ float Ws[12][129];   // stride 129 -> bank (j+k)%32, conflict-free
    __shared__ float hs[16][132];   // stride 132 for float4 staging
    int tid = threadIdx.x;
    for (int f = tid; f < 12 * 128; f += 256) {
        int j = f >> 7, k = f & 127;
        Ws[j][k] = (j < 6) ? Wl[j * 128 + k] : Wr[(j - 6) * 128 + k];
    }
    int node0 = blockIdx.x * 16;
#pragma unroll
    for (int t = 0; t < 2; ++t) {
        int f = tid + t * 256;   // 0..511
        int r = f >> 5;          // 0..15
        int c4 = (f & 31) * 4;
        int gn = node0 + r;
        float4 v = make_float4(0.f, 0.f, 0.f, 0.f);
        if (gn < M) v = *(const float4*)&h[(size_t)gn * 128 + c4];
        *(float4*)&hs[r][c4] = v;
    }
    __syncthreads();
    int ln = tid >> 4;   // 0..15
    int j = tid & 15;    // active j<12
    int gn = node0 + ln;
    if (j < 12 && gn < M) {
        float acc = 0.f;
#pragma unroll
        for (int k = 0; k < 128; ++k) acc += hs[ln][k] * Ws[j][k];
        if (j >= 6) acc += b3[j - 6];
        zr[(size_t)gn * 12 + j] = acc;
    }
}

// ------------------------------------------- final: out[n][j] = mean_s z[s][j] + r[n][j]
__global__ void out_kernel(const float* __restrict__ zr, const int* __restrict__ row_off,
                           const int* __restrict__ csr, float* __restrict__ out, int M) {
    int idx = blockIdx.x * blockDim.x + threadIdx.x;
    int node = idx >> 3;   // 8 threads per node
    int j = idx & 7;
    if (node >= M || j >= 6) return;
    int beg = row_off[node], end = row_off[node + 1];
    float acc = 0.f;
    for (int i = beg; i < end; ++i) {
        int s = csr[i];
        acc += zr[(size_t)s * 12 + j];
    }
    float inv = (end > beg) ? 1.0f / (float)(end - beg) : 0.0f;
    out[(size_t)node * 6 + j] = acc * inv + zr[(size_t)node * 12 + 6 + j];
}

// ---------------------------------------------------------------- launch
static inline size_t align_up(size_t x, size_t a) { return (x + a - 1) & ~(a - 1); }

extern "C" void kernel_launch(void* const* d_in, const int* in_sizes, int n_in,
                              void* d_out, int out_size, void* d_ws, size_t ws_size,
                              hipStream_t stream) {
    const float* x = (const float*)d_in[0];
    const int* ei = (const int*)d_in[1];
    const float* Wl1 = (const float*)d_in[2];
    const float* Wr1 = (const float*)d_in[3];
    const float* b1 = (const float*)d_in[4];
    const float* Wl2 = (const float*)d_in[5];
    const float* Wr2 = (const float*)d_in[6];
    const float* b2 = (const float*)d_in[7];
    const float* Wl3 = (const float*)d_in[8];
    const float* Wr3 = (const float*)d_in[9];
    const float* b3 = (const float*)d_in[10];

    const int N = in_sizes[0] / 128;   // 100000
    const int E = in_sizes[1] / 2;     // 3200000
    const int* src = ei;
    const int* dst = ei + E;

    // workspace layout
    char* ws = (char*)d_ws;
    size_t off = 0;
    int* cnt = (int*)(ws + off);      off = align_up(off + (size_t)N * 4, 512);
    int* row_off = (int*)(ws + off);  off = align_up(off + (size_t)(N + 1) * 4, 512);
    int* cursor = (int*)(ws + off);   off = align_up(off + (size_t)N * 4, 512);
    int* csr_src = (int*)(ws + off);  off = align_up(off + (size_t)E * 4, 512);
    float* aggn = (float*)(ws + off); off = align_up(off + (size_t)N * 128 * 4, 512);
    float* h1 = (float*)(ws + off);   off = align_up(off + (size_t)N * 128 * 4, 512);
    float* h2 = (float*)(ws + off);   off = align_up(off + (size_t)N * 128 * 4, 512);
    float* zr = (float*)(ws + off);   off = align_up(off + (size_t)N * 12 * 4, 512);
    (void)ws_size;

    // CSR build (reused by all 3 layers)
    hipMemsetAsync(cnt, 0, (size_t)N * 4, stream);
    count_kernel<<<(E + 255) / 256, 256, 0, stream>>>(dst, E, cnt);
    scan_kernel<<<1, 256, 0, stream>>>(cnt, row_off, cursor, N);
    fill_kernel<<<(E + 255) / 256, 256, 0, stream>>>(src, dst, E, cursor, csr_src);

    int aggGrid = (N + 3) / 4;
    int gemmGrid = (N + BM - 1) / BM;

    // layer 1
    agg_kernel<<<aggGrid, 256, 0, stream>>>(x, row_off, csr_src, aggn, N);
    gemm_dual<<<gemmGrid, 256, 0, stream>>>(aggn, x, Wl1, Wr1, b1, h1, N, 1);
    // layer 2
    agg_kernel<<<aggGrid, 256, 0, stream>>>(h1, row_off, csr_src, aggn, N);
    gemm_dual<<<gemmGrid, 256, 0, stream>>>(aggn, h1, Wl2, Wr2, b2, h2, N, 1);
    // layer 3: transform-then-aggregate (6-dim, 21x less gather traffic)
    lin3_kernel<<<(N + 15) / 16, 256, 0, stream>>>(h2, Wl3, Wr3, b3, zr, N);
    out_kernel<<<(N * 8 + 255) / 256, 256, 0, stream>>>(zr, row_off, csr_src, (float*)d_out, N);
}

// Round 2
// 1283.084 us; speedup vs baseline: 1.0543x; 1.0543x over previous
//
#include <hip/hip_runtime.h>
#include <hip/hip_bf16.h>

#define N_NODES 100000

// ---------------------------------------------------------------- CSR build
// XCD-range-partitioned count: blockIdx%8 -> group g handles dst in
// [g*npg, (g+1)*npg). Under round-robin workgroup->XCD dispatch this keeps
// each XCD's atomics/writes in a small L2-resident slice. Correct regardless
// of actual placement (locality heuristic only).
__global__ __launch_bounds__(256) void count_part(const int* __restrict__ dst, int E,
                                                  int* __restrict__ cnt, int npg,
                                                  int blocks_per_g, int N) {
    int g = blockIdx.x & 7;
    int bg = blockIdx.x >> 3;
    int lo = g * npg;
    int hi = min(lo + npg, N);
    for (int i = bg * 256 + threadIdx.x; i < E; i += blocks_per_g * 256) {
        int d = dst[i];
        if (d >= lo && d < hi) atomicAdd(&cnt[d], 1);
    }
}

// single block, 256 threads: exclusive prefix sum of cnt[0..n) -> row_off, cursor
__global__ void scan_kernel(const int* __restrict__ cnt, int* __restrict__ row_off,
                            int* __restrict__ cursor, int n) {
    __shared__ int sums[256];
    int tid = threadIdx.x;
    int per = (n + 255) / 256;
    int b = tid * per;
    int e = min(b + per, n);
    int s = 0;
    for (int i = b; i < e; ++i) s += cnt[i];
    sums[tid] = s;
    __syncthreads();
    for (int off = 1; off < 256; off <<= 1) {
        int v = 0;
        if (tid >= off) v = sums[tid - off];
        __syncthreads();
        if (tid >= off) sums[tid] += v;
        __syncthreads();
    }
    int run = (tid > 0) ? sums[tid - 1] : 0;
    for (int i = b; i < e; ++i) {
        int c = cnt[i];
        row_off[i] = run;
        cursor[i] = run;
        run += c;
    }
    if (tid == 255) row_off[n] = run;
}

// XCD-range-partitioned fill: same partitioning as count_part. Writes to
// csr_src land in a ~1.6MB per-group slice -> full line merging in L2,
// killing the 16x write amplification seen with the flat scatter.
__global__ __launch_bounds__(256) void fill_part(const int* __restrict__ src,
                                                 const int* __restrict__ dst, int E,
                                                 int* __restrict__ cursor,
                                                 int* __restrict__ csr_src, int npg,
                                                 int blocks_per_g, int N) {
    int g = blockIdx.x & 7;
    int bg = blockIdx.x >> 3;
    int lo = g * npg;
    int hi = min(lo + npg, N);
    for (int i = bg * 256 + threadIdx.x; i < E; i += blocks_per_g * 256) {
        int d = dst[i];
        int s = src[i];
        if (d >= lo && d < hi) {
            int p = atomicAdd(&cursor[d], 1);
            csr_src[p] = s;
        }
    }
}

// ------------------------------------------------------- mean aggregation (F=128)
// one wave per dst node; lane handles float2 (features 2*lane, 2*lane+1)
__global__ __launch_bounds__(256) void agg_kernel(const float* __restrict__ feat,
                                                  const int* __restrict__ row_off,
                                                  const int* __restrict__ csr,
                                                  float* __restrict__ outf, int M) {
    int node = blockIdx.x * 4 + (threadIdx.x >> 6);
    if (node >= M) return;
    int lane = threadIdx.x & 63;
    int beg = row_off[node], end = row_off[node + 1];
    const float2* f2 = (const float2*)feat;
    float sx = 0.f, sy = 0.f;
    int i = beg;
    for (; i + 4 <= end; i += 4) {
        int s0 = csr[i], s1 = csr[i + 1], s2 = csr[i + 2], s3 = csr[i + 3];
        float2 v0 = f2[(size_t)s0 * 64 + lane];
        float2 v1 = f2[(size_t)s1 * 64 + lane];
        float2 v2 = f2[(size_t)s2 * 64 + lane];
        float2 v3 = f2[(size_t)s3 * 64 + lane];
        sx += v0.x + v1.x + v2.x + v3.x;
        sy += v0.y + v1.y + v2.y + v3.y;
    }
    for (; i < end; ++i) {
        int s = csr[i];
        float2 v = f2[(size_t)s * 64 + lane];
        sx += v.x;
        sy += v.y;
    }
    float inv = (end > beg) ? 1.0f / (float)(end - beg) : 0.0f;
    float2 o;
    o.x = sx * inv;
    o.y = sy * inv;
    ((float2*)outf)[(size_t)node * 64 + lane] = o;
}

// --------------------------------------------- fused dual GEMM: out = act(A1@W1^T + A2@W2^T + b)
// A1,A2: [M,128]; W1,W2: [128,128] row-major (out_j uses W[j][k]); out: [M,128]
#define BM 64
#define KB 32
__global__ __launch_bounds__(256) void gemm_dual(const float* __restrict__ A1,
                                                 const float* __restrict__ A2,
                                                 const float* __restrict__ W1,
                                                 const float* __restrict__ W2,
                                                 const float* __restrict__ bias,
                                                 float* __restrict__ out, int M, int relu) {
    __shared__ float As[KB][BM + 4];    // stride 68 floats (272 B, 16B-aligned)
    __shared__ float Ws[KB][128 + 4];   // stride 132 floats (528 B, 16B-aligned)
    int tid = threadIdx.x;
    int row0 = blockIdx.x * BM;
    int tr = tid >> 5;   // 0..7
    int tc = tid & 31;   // 0..31
    int r0 = tr * 8;
    int c0 = tc * 4;
    float acc[8][4];
#pragma unroll
    for (int i = 0; i < 8; ++i)
#pragma unroll
        for (int c = 0; c < 4; ++c) acc[i][c] = 0.f;

    for (int half = 0; half < 2; ++half) {
        const float* A = half ? A2 : A1;
        const float* W = half ? W2 : W1;
        for (int kc = 0; kc < 128; kc += KB) {
            // stage A tile 64x32 (transposed into As[k][m])
#pragma unroll
            for (int t = 0; t < 2; ++t) {
                int f = tid + t * 256;   // 0..511
                int r = f >> 3;          // 0..63
                int c4 = (f & 7) * 4;    // 0,4,..,28
                int gr = row0 + r;
                float4 v = make_float4(0.f, 0.f, 0.f, 0.f);
                if (gr < M) v = *(const float4*)&A[(size_t)gr * 128 + kc + c4];
                As[c4 + 0][r] = v.x;
                As[c4 + 1][r] = v.y;
                As[c4 + 2][r] = v.z;
                As[c4 + 3][r] = v.w;
            }
            // stage W tile 128x32 (transposed into Ws[k][j])
#pragma unroll
            for (int t = 0; t < 4; ++t) {
                int f = tid + t * 256;   // 0..1023
                int j = f >> 3;          // 0..127
                int c4 = (f & 7) * 4;
                float4 v = *(const float4*)&W[(size_t)j * 128 + kc + c4];
                Ws[c4 + 0][j] = v.x;
                Ws[c4 + 1][j] = v.y;
                Ws[c4 + 2][j] = v.z;
                Ws[c4 + 3][j] = v.w;
            }
            __syncthreads();
#pragma unroll
            for (int k = 0; k < KB; ++k) {
                float4 a0 = *(const float4*)&As[k][r0];
                float4 a1 = *(const float4*)&As[k][r0 + 4];
                float4 bv = *(const float4*)&Ws[k][c0];
                float av[8] = {a0.x, a0.y, a0.z, a0.w, a1.x, a1.y, a1.z, a1.w};
                float bb[4] = {bv.x, bv.y, bv.z, bv.w};
#pragma unroll
                for (int i = 0; i < 8; ++i)
#pragma unroll
                    for (int c = 0; c < 4; ++c) acc[i][c] += av[i] * bb[c];
            }
            __syncthreads();
        }
    }
    // epilogue
#pragma unroll
    for (int i = 0; i < 8; ++i) {
        int gr = row0 + r0 + i;
        if (gr < M) {
            float4 o;
            o.x = acc[i][0] + bias[c0 + 0];
            o.y = acc[i][1] + bias[c0 + 1];
            o.z = acc[i][2] + bias[c0 + 2];
            o.w = acc[i][3] + bias[c0 + 3];
            if (relu) {
                o.x = fmaxf(o.x, 0.f);
                o.y = fmaxf(o.y, 0.f);
                o.z = fmaxf(o.z, 0.f);
                o.w = fmaxf(o.w, 0.f);
            }
            *(float4*)&out[(size_t)gr * 128 + c0] = o;
        }
    }
}

// ------------------------------------- layer 3 transform: zr[n][0..5]=h@Wl3^T, [6..11]=h@Wr3^T+b3
__global__ __launch_bounds__(256) void lin3_kernel(const float* __restrict__ h,
                                                   const float* __restrict__ Wl,
                                                   const float* __restrict__ Wr,
                                                   const float* __restrict__ b3,
                                                   float* __restrict__ zr, int M) {
    __shared__ float Ws[12][129];   // stride 129 -> bank (j+k)%32, conflict-free
    __shared__ float hs[16][132];   // stride 132 for float4 staging
    int tid = threadIdx.x;
    for (int f = tid; f < 12 * 128; f += 256) {
        int j = f >> 7, k = f & 127;
        Ws[j][k] = (j < 6) ? Wl[j * 128 + k] : Wr[(j - 6) * 128 + k];
    }
    int node0 = blockIdx.x * 16;
#pragma unroll
    for (int t = 0; t < 2; ++t) {
        int f = tid + t * 256;   // 0..511
        int r = f >> 5;          // 0..15
        int c4 = (f & 31) * 4;
        int gn = node0 + r;
        float4 v = make_float4(0.f, 0.f, 0.f, 0.f);
        if (gn < M) v = *(const float4*)&h[(size_t)gn * 128 + c4];
        *(float4*)&hs[r][c4] = v;
    }
    __syncthreads();
    int ln = tid >> 4;   // 0..15
    int j = tid & 15;    // active j<12
    int gn = node0 + ln;
    if (j < 12 && gn < M) {
        float acc = 0.f;
#pragma unroll
        for (int k = 0; k < 128; ++k) acc += hs[ln][k] * Ws[j][k];
        if (j >= 6) acc += b3[j - 6];
        zr[(size_t)gn * 12 + j] = acc;
    }
}

// ------------------------------------------- final: out[n][j] = mean_s z[s][j] + r[n][j]
__global__ void out_kernel(const float* __restrict__ zr, const int* __restrict__ row_off,
                           const int* __restrict__ csr, float* __restrict__ out, int M) {
    int idx = blockIdx.x * blockDim.x + threadIdx.x;
    int node = idx >> 3;   // 8 threads per node
    int j = idx & 7;
    if (node >= M || j >= 6) return;
    int beg = row_off[node], end = row_off[node + 1];
    float acc = 0.f;
    for (int i = beg; i < end; ++i) {
        int s = csr[i];
        acc += zr[(size_t)s * 12 + j];
    }
    float inv = (end > beg) ? 1.0f / (float)(end - beg) : 0.0f;
    out[(size_t)node * 6 + j] = acc * inv + zr[(size_t)node * 12 + 6 + j];
}

// ---------------------------------------------------------------- launch
static inline size_t align_up(size_t x, size_t a) { return (x + a - 1) & ~(a - 1); }

extern "C" void kernel_launch(void* const* d_in, const int* in_sizes, int n_in,
                              void* d_out, int out_size, void* d_ws, size_t ws_size,
                              hipStream_t stream) {
    const float* x = (const float*)d_in[0];
    const int* ei = (const int*)d_in[1];
    const float* Wl1 = (const float*)d_in[2];
    const float* Wr1 = (const float*)d_in[3];
    const float* b1 = (const float*)d_in[4];
    const float* Wl2 = (const float*)d_in[5];
    const float* Wr2 = (const float*)d_in[6];
    const float* b2 = (const float*)d_in[7];
    const float* Wl3 = (const float*)d_in[8];
    const float* Wr3 = (const float*)d_in[9];
    const float* b3 = (const float*)d_in[10];

    const int N = in_sizes[0] / 128;   // 100000
    const int E = in_sizes[1] / 2;     // 3200000
    const int* src = ei;
    const int* dst = ei + E;

    // workspace layout
    char* ws = (char*)d_ws;
    size_t off = 0;
    int* cnt = (int*)(ws + off);      off = align_up(off + (size_t)N * 4, 512);
    int* row_off = (int*)(ws + off);  off = align_up(off + (size_t)(N + 1) * 4, 512);
    int* cursor = (int*)(ws + off);   off = align_up(off + (size_t)N * 4, 512);
    int* csr_src = (int*)(ws + off);  off = align_up(off + (size_t)E * 4, 512);
    float* aggn = (float*)(ws + off); off = align_up(off + (size_t)N * 128 * 4, 512);
    float* h1 = (float*)(ws + off);   off = align_up(off + (size_t)N * 128 * 4, 512);
    float* h2 = (float*)(ws + off);   off = align_up(off + (size_t)N * 128 * 4, 512);
    float* zr = (float*)(ws + off);   off = align_up(off + (size_t)N * 12 * 4, 512);
    (void)ws_size;

    // CSR build (reused by all 3 layers), XCD-range-partitioned
    const int npg = (N + 7) / 8;           // nodes per group
    const int blocks_per_g = 256;          // blocks per group
    const int part_grid = 8 * blocks_per_g;
    hipMemsetAsync(cnt, 0, (size_t)N * 4, stream);
    count_part<<<part_grid, 256, 0, stream>>>(dst, E, cnt, npg, blocks_per_g, N);
    scan_kernel<<<1, 256, 0, stream>>>(cnt, row_off, cursor, N);
    fill_part<<<part_grid, 256, 0, stream>>>(src, dst, E, cursor, csr_src, npg, blocks_per_g, N);

    int aggGrid = (N + 3) / 4;
    int gemmGrid = (N + BM - 1) / BM;

    // layer 1
    agg_kernel<<<aggGrid, 256, 0, stream>>>(x, row_off, csr_src, aggn, N);
    gemm_dual<<<gemmGrid, 256, 0, stream>>>(aggn, x, Wl1, Wr1, b1, h1, N, 1);
    // layer 2
    agg_kernel<<<aggGrid, 256, 0, stream>>>(h1, row_off, csr_src, aggn, N);
    gemm_dual<<<gemmGrid, 256, 0, stream>>>(aggn, h1, Wl2, Wr2, b2, h2, N, 1);
    // layer 3: transform-then-aggregate (6-dim, 21x less gather traffic)
    lin3_kernel<<<(N + 15) / 16, 256, 0, stream>>>(h2, Wl3, Wr3, b3, zr, N);
    out_kernel<<<(N * 8 + 255) / 256, 256, 0, stream>>>(zr, row_off, csr_src, (float*)d_out, N);
}

// Round 3
// 1076.941 us; speedup vs baseline: 1.2561x; 1.1914x over previous
//
#include <hip/hip_runtime.h>
#include <hip/hip_bf16.h>

#define N_NODES 100000

// ---------------------------------------------------------------- CSR build
// XCD-range-partitioned count: blockIdx%8 -> group g handles dst in
// [g*npg, (g+1)*npg). Under round-robin workgroup->XCD dispatch this keeps
// each XCD's atomics/writes in a small L2-resident slice. Correct regardless
// of actual placement (locality heuristic only).
__global__ __launch_bounds__(256) void count_part(const int* __restrict__ dst, int E,
                                                  int* __restrict__ cnt, int npg,
                                                  int blocks_per_g, int N) {
    int g = blockIdx.x & 7;
    int bg = blockIdx.x >> 3;
    int lo = g * npg;
    int hi = min(lo + npg, N);
    for (int i = bg * 256 + threadIdx.x; i < E; i += blocks_per_g * 256) {
        int d = dst[i];
        if (d >= lo && d < hi) atomicAdd(&cnt[d], 1);
    }
}

// ---------------- grid-parallel exclusive scan (3 kernels, 1024 elems/block)
#define SCHUNK 1024

// phase 1: block-local exclusive scan of cnt -> row_off, block total -> block_sums
__global__ __launch_bounds__(256) void scan_blocks(const int* __restrict__ cnt,
                                                   int* __restrict__ row_off,
                                                   int* __restrict__ block_sums, int n) {
    __shared__ int ts[256];
    int tid = threadIdx.x;
    int base = blockIdx.x * SCHUNK + tid * 4;
    int v[4];
    int s = 0;
#pragma unroll
    for (int j = 0; j < 4; ++j) {
        int i = base + j;
        v[j] = (i < n) ? cnt[i] : 0;
        s += v[j];
    }
    ts[tid] = s;
    __syncthreads();
    for (int off = 1; off < 256; off <<= 1) {
        int t = 0;
        if (tid >= off) t = ts[tid - off];
        __syncthreads();
        if (tid >= off) ts[tid] += t;
        __syncthreads();
    }
    int run = (tid > 0) ? ts[tid - 1] : 0;
    if (tid == 255) block_sums[blockIdx.x] = ts[255];
#pragma unroll
    for (int j = 0; j < 4; ++j) {
        int i = base + j;
        if (i < n) row_off[i] = run;
        run += v[j];
    }
}

// phase 2: single block, exclusive scan of block_sums (nb <= 256), grand total -> row_off[n]
__global__ __launch_bounds__(256) void scan_sums(int* __restrict__ block_sums, int nb,
                                                 int* __restrict__ row_off, int n) {
    __shared__ int ts[256];
    int tid = threadIdx.x;
    int v = (tid < nb) ? block_sums[tid] : 0;
    ts[tid] = v;
    __syncthreads();
    for (int off = 1; off < 256; off <<= 1) {
        int t = 0;
        if (tid >= off) t = ts[tid - off];
        __syncthreads();
        if (tid >= off) ts[tid] += t;
        __syncthreads();
    }
    if (tid < nb) block_sums[tid] = (tid > 0) ? ts[tid - 1] : 0;
    if (tid == 255) row_off[n] = ts[255];
}

// phase 3: add block offsets; write final row_off and cursor
__global__ __launch_bounds__(256) void scan_add(int* __restrict__ row_off,
                                                int* __restrict__ cursor,
                                                const int* __restrict__ block_sums, int n) {
    int tid = threadIdx.x;
    int off = block_sums[blockIdx.x];
    int base = blockIdx.x * SCHUNK + tid * 4;
#pragma unroll
    for (int j = 0; j < 4; ++j) {
        int i = base + j;
        if (i < n) {
            int r = row_off[i] + off;
            row_off[i] = r;
            cursor[i] = r;
        }
    }
}

// XCD-range-partitioned fill: same partitioning as count_part. Writes to
// csr_src land in a ~1.6MB per-group slice -> full line merging in L2,
// killing the 16x write amplification seen with the flat scatter.
__global__ __launch_bounds__(256) void fill_part(const int* __restrict__ src,
                                                 const int* __restrict__ dst, int E,
                                                 int* __restrict__ cursor,
                                                 int* __restrict__ csr_src, int npg,
                                                 int blocks_per_g, int N) {
    int g = blockIdx.x & 7;
    int bg = blockIdx.x >> 3;
    int lo = g * npg;
    int hi = min(lo + npg, N);
    for (int i = bg * 256 + threadIdx.x; i < E; i += blocks_per_g * 256) {
        int d = dst[i];
        int s = src[i];
        if (d >= lo && d < hi) {
            int p = atomicAdd(&cursor[d], 1);
            csr_src[p] = s;
        }
    }
}

// ------------------------------------------------------- mean aggregation (F=128)
// one wave per dst node; lane handles float2 (features 2*lane, 2*lane+1)
__global__ __launch_bounds__(256) void agg_kernel(const float* __restrict__ feat,
                                                  const int* __restrict__ row_off,
                                                  const int* __restrict__ csr,
                                                  float* __restrict__ outf, int M) {
    int node = blockIdx.x * 4 + (threadIdx.x >> 6);
    if (node >= M) return;
    int lane = threadIdx.x & 63;
    int beg = row_off[node], end = row_off[node + 1];
    const float2* f2 = (const float2*)feat;
    float sx = 0.f, sy = 0.f;
    int i = beg;
    for (; i + 4 <= end; i += 4) {
        int s0 = csr[i], s1 = csr[i + 1], s2 = csr[i + 2], s3 = csr[i + 3];
        float2 v0 = f2[(size_t)s0 * 64 + lane];
        float2 v1 = f2[(size_t)s1 * 64 + lane];
        float2 v2 = f2[(size_t)s2 * 64 + lane];
        float2 v3 = f2[(size_t)s3 * 64 + lane];
        sx += v0.x + v1.x + v2.x + v3.x;
        sy += v0.y + v1.y + v2.y + v3.y;
    }
    for (; i < end; ++i) {
        int s = csr[i];
        float2 v = f2[(size_t)s * 64 + lane];
        sx += v.x;
        sy += v.y;
    }
    float inv = (end > beg) ? 1.0f / (float)(end - beg) : 0.0f;
    float2 o;
    o.x = sx * inv;
    o.y = sy * inv;
    ((float2*)outf)[(size_t)node * 64 + lane] = o;
}

// --------------------------------------------- fused dual GEMM: out = act(A1@W1^T + A2@W2^T + b)
// A1,A2: [M,128]; W1,W2: [128,128] row-major (out_j uses W[j][k]); out: [M,128]
#define BM 64
#define KB 32
__global__ __launch_bounds__(256) void gemm_dual(const float* __restrict__ A1,
                                                 const float* __restrict__ A2,
                                                 const float* __restrict__ W1,
                                                 const float* __restrict__ W2,
                                                 const float* __restrict__ bias,
                                                 float* __restrict__ out, int M, int relu) {
    __shared__ float As[KB][BM + 4];    // stride 68 floats (272 B, 16B-aligned)
    __shared__ float Ws[KB][128 + 4];   // stride 132 floats (528 B, 16B-aligned)
    int tid = threadIdx.x;
    int row0 = blockIdx.x * BM;
    int tr = tid >> 5;   // 0..7
    int tc = tid & 31;   // 0..31
    int r0 = tr * 8;
    int c0 = tc * 4;
    float acc[8][4];
#pragma unroll
    for (int i = 0; i < 8; ++i)
#pragma unroll
        for (int c = 0; c < 4; ++c) acc[i][c] = 0.f;

    for (int half = 0; half < 2; ++half) {
        const float* A = half ? A2 : A1;
        const float* W = half ? W2 : W1;
        for (int kc = 0; kc < 128; kc += KB) {
            // stage A tile 64x32 (transposed into As[k][m])
#pragma unroll
            for (int t = 0; t < 2; ++t) {
                int f = tid + t * 256;   // 0..511
                int r = f >> 3;          // 0..63
                int c4 = (f & 7) * 4;    // 0,4,..,28
                int gr = row0 + r;
                float4 v = make_float4(0.f, 0.f, 0.f, 0.f);
                if (gr < M) v = *(const float4*)&A[(size_t)gr * 128 + kc + c4];
                As[c4 + 0][r] = v.x;
                As[c4 + 1][r] = v.y;
                As[c4 + 2][r] = v.z;
                As[c4 + 3][r] = v.w;
            }
            // stage W tile 128x32 (transposed into Ws[k][j])
#pragma unroll
            for (int t = 0; t < 4; ++t) {
                int f = tid + t * 256;   // 0..1023
                int j = f >> 3;          // 0..127
                int c4 = (f & 7) * 4;
                float4 v = *(const float4*)&W[(size_t)j * 128 + kc + c4];
                Ws[c4 + 0][j] = v.x;
                Ws[c4 + 1][j] = v.y;
                Ws[c4 + 2][j] = v.z;
                Ws[c4 + 3][j] = v.w;
            }
            __syncthreads();
#pragma unroll
            for (int k = 0; k < KB; ++k) {
                float4 a0 = *(const float4*)&As[k][r0];
                float4 a1 = *(const float4*)&As[k][r0 + 4];
                float4 bv = *(const float4*)&Ws[k][c0];
                float av[8] = {a0.x, a0.y, a0.z, a0.w, a1.x, a1.y, a1.z, a1.w};
                float bb[4] = {bv.x, bv.y, bv.z, bv.w};
#pragma unroll
                for (int i = 0; i < 8; ++i)
#pragma unroll
                    for (int c = 0; c < 4; ++c) acc[i][c] += av[i] * bb[c];
            }
            __syncthreads();
        }
    }
    // epilogue
#pragma unroll
    for (int i = 0; i < 8; ++i) {
        int gr = row0 + r0 + i;
        if (gr < M) {
            float4 o;
            o.x = acc[i][0] + bias[c0 + 0];
            o.y = acc[i][1] + bias[c0 + 1];
            o.z = acc[i][2] + bias[c0 + 2];
            o.w = acc[i][3] + bias[c0 + 3];
            if (relu) {
                o.x = fmaxf(o.x, 0.f);
                o.y = fmaxf(o.y, 0.f);
                o.z = fmaxf(o.z, 0.f);
                o.w = fmaxf(o.w, 0.f);
            }
            *(float4*)&out[(size_t)gr * 128 + c0] = o;
        }
    }
}

// ------------------------------------- layer 3 transform: zr[n][0..5]=h@Wl3^T, [6..11]=h@Wr3^T+b3
__global__ __launch_bounds__(256) void lin3_kernel(const float* __restrict__ h,
                                                   const float* __restrict__ Wl,
                                                   const float* __restrict__ Wr,
                                                   const float* __restrict__ b3,
                                                   float* __restrict__ zr, int M) {
    __shared__ float Ws[12][129];   // stride 129 -> bank (j+k)%32, conflict-free
    __shared__ float hs[16][132];   // stride 132 for float4 staging
    int tid = threadIdx.x;
    for (int f = tid; f < 12 * 128; f += 256) {
        int j = f >> 7, k = f & 127;
        Ws[j][k] = (j < 6) ? Wl[j * 128 + k] : Wr[(j - 6) * 128 + k];
    }
    int node0 = blockIdx.x * 16;
#pragma unroll
    for (int t = 0; t < 2; ++t) {
        int f = tid + t * 256;   // 0..511
        int r = f >> 5;          // 0..15
        int c4 = (f & 31) * 4;
        int gn = node0 + r;
        float4 v = make_float4(0.f, 0.f, 0.f, 0.f);
        if (gn < M) v = *(const float4*)&h[(size_t)gn * 128 + c4];
        *(float4*)&hs[r][c4] = v;
    }
    __syncthreads();
    int ln = tid >> 4;   // 0..15
    int j = tid & 15;    // active j<12
    int gn = node0 + ln;
    if (j < 12 && gn < M) {
        float acc = 0.f;
#pragma unroll
        for (int k = 0; k < 128; ++k) acc += hs[ln][k] * Ws[j][k];
        if (j >= 6) acc += b3[j - 6];
        zr[(size_t)gn * 12 + j] = acc;
    }
}

// ------------------------------------------- final: out[n][j] = mean_s z[s][j] + r[n][j]
__global__ void out_kernel(const float* __restrict__ zr, const int* __restrict__ row_off,
                           const int* __restrict__ csr, float* __restrict__ out, int M) {
    int idx = blockIdx.x * blockDim.x + threadIdx.x;
    int node = idx >> 3;   // 8 threads per node
    int j = idx & 7;
    if (node >= M || j >= 6) return;
    int beg = row_off[node], end = row_off[node + 1];
    float acc = 0.f;
    for (int i = beg; i < end; ++i) {
        int s = csr[i];
        acc += zr[(size_t)s * 12 + j];
    }
    float inv = (end > beg) ? 1.0f / (float)(end - beg) : 0.0f;
    out[(size_t)node * 6 + j] = acc * inv + zr[(size_t)node * 12 + 6 + j];
}

// ---------------------------------------------------------------- launch
static inline size_t align_up(size_t x, size_t a) { return (x + a - 1) & ~(a - 1); }

extern "C" void kernel_launch(void* const* d_in, const int* in_sizes, int n_in,
                              void* d_out, int out_size, void* d_ws, size_t ws_size,
                              hipStream_t stream) {
    const float* x = (const float*)d_in[0];
    const int* ei = (const int*)d_in[1];
    const float* Wl1 = (const float*)d_in[2];
    const float* Wr1 = (const float*)d_in[3];
    const float* b1 = (const float*)d_in[4];
    const float* Wl2 = (const float*)d_in[5];
    const float* Wr2 = (const float*)d_in[6];
    const float* b2 = (const float*)d_in[7];
    const float* Wl3 = (const float*)d_in[8];
    const float* Wr3 = (const float*)d_in[9];
    const float* b3 = (const float*)d_in[10];

    const int N = in_sizes[0] / 128;   // 100000
    const int E = in_sizes[1] / 2;     // 3200000
    const int* src = ei;
    const int* dst = ei + E;

    // workspace layout
    char* ws = (char*)d_ws;
    size_t off = 0;
    int* cnt = (int*)(ws + off);        off = align_up(off + (size_t)N * 4, 512);
    int* row_off = (int*)(ws + off);    off = align_up(off + (size_t)(N + 1) * 4, 512);
    int* cursor = (int*)(ws + off);     off = align_up(off + (size_t)N * 4, 512);
    int* block_sums = (int*)(ws + off); off = align_up(off + 512 * 4, 512);
    int* csr_src = (int*)(ws + off);    off = align_up(off + (size_t)E * 4, 512);
    float* aggn = (float*)(ws + off);   off = align_up(off + (size_t)N * 128 * 4, 512);
    float* h1 = (float*)(ws + off);     off = align_up(off + (size_t)N * 128 * 4, 512);
    float* h2 = (float*)(ws + off);     off = align_up(off + (size_t)N * 128 * 4, 512);
    float* zr = (float*)(ws + off);     off = align_up(off + (size_t)N * 12 * 4, 512);
    (void)ws_size;

    // CSR build (reused by all 3 layers), XCD-range-partitioned
    const int npg = (N + 7) / 8;           // nodes per group
    const int blocks_per_g = 256;          // blocks per group
    const int part_grid = 8 * blocks_per_g;
    hipMemsetAsync(cnt, 0, (size_t)N * 4, stream);
    count_part<<<part_grid, 256, 0, stream>>>(dst, E, cnt, npg, blocks_per_g, N);

    // grid-parallel exclusive scan: cnt -> row_off (+cursor), total -> row_off[N]
    const int nscan = (N + SCHUNK - 1) / SCHUNK;   // 98 blocks (<=256)
    scan_blocks<<<nscan, 256, 0, stream>>>(cnt, row_off, block_sums, N);
    scan_sums<<<1, 256, 0, stream>>>(block_sums, nscan, row_off, N);
    scan_add<<<nscan, 256, 0, stream>>>(row_off, cursor, block_sums, N);

    fill_part<<<part_grid, 256, 0, stream>>>(src, dst, E, cursor, csr_src, npg, blocks_per_g, N);

    int aggGrid = (N + 3) / 4;
    int gemmGrid = (N + BM - 1) / BM;

    // layer 1
    agg_kernel<<<aggGrid, 256, 0, stream>>>(x, row_off, csr_src, aggn, N);
    gemm_dual<<<gemmGrid, 256, 0, stream>>>(aggn, x, Wl1, Wr1, b1, h1, N, 1);
    // layer 2
    agg_kernel<<<aggGrid, 256, 0, stream>>>(h1, row_off, csr_src, aggn, N);
    gemm_dual<<<gemmGrid, 256, 0, stream>>>(aggn, h1, Wl2, Wr2, b2, h2, N, 1);
    // layer 3: transform-then-aggregate (6-dim, 21x less gather traffic)
    lin3_kernel<<<(N + 15) / 16, 256, 0, stream>>>(h2, Wl3, Wr3, b3, zr, N);
    out_kernel<<<(N * 8 + 255) / 256, 256, 0, stream>>>(zr, row_off, csr_src, (float*)d_out, N);
}

// Round 4
// 905.306 us; speedup vs baseline: 1.4943x; 1.1896x over previous
//
#include <hip/hip_runtime.h>
#include <hip/hip_bf16.h>

#define N_NODES 100000

// ---------------------------------------------------------------- CSR build
// XCD-range-partitioned count/fill (see R1 post-mortem: kills 16x write amp).
__global__ __launch_bounds__(256) void count_part(const int* __restrict__ dst, int E,
                                                  int* __restrict__ cnt, int npg,
                                                  int blocks_per_g, int N) {
    int g = blockIdx.x & 7;
    int bg = blockIdx.x >> 3;
    int lo = g * npg;
    int hi = min(lo + npg, N);
    for (int i = bg * 256 + threadIdx.x; i < E; i += blocks_per_g * 256) {
        int d = dst[i];
        if (d >= lo && d < hi) atomicAdd(&cnt[d], 1);
    }
}

// ---------------- grid-parallel exclusive scan (3 kernels, 1024 elems/block)
#define SCHUNK 1024

__global__ __launch_bounds__(256) void scan_blocks(const int* __restrict__ cnt,
                                                   int* __restrict__ row_off,
                                                   int* __restrict__ block_sums, int n) {
    __shared__ int ts[256];
    int tid = threadIdx.x;
    int base = blockIdx.x * SCHUNK + tid * 4;
    int v[4];
    int s = 0;
#pragma unroll
    for (int j = 0; j < 4; ++j) {
        int i = base + j;
        v[j] = (i < n) ? cnt[i] : 0;
        s += v[j];
    }
    ts[tid] = s;
    __syncthreads();
    for (int off = 1; off < 256; off <<= 1) {
        int t = 0;
        if (tid >= off) t = ts[tid - off];
        __syncthreads();
        if (tid >= off) ts[tid] += t;
        __syncthreads();
    }
    int run = (tid > 0) ? ts[tid - 1] : 0;
    if (tid == 255) block_sums[blockIdx.x] = ts[255];
#pragma unroll
    for (int j = 0; j < 4; ++j) {
        int i = base + j;
        if (i < n) row_off[i] = run;
        run += v[j];
    }
}

__global__ __launch_bounds__(256) void scan_sums(int* __restrict__ block_sums, int nb,
                                                 int* __restrict__ row_off, int n) {
    __shared__ int ts[256];
    int tid = threadIdx.x;
    int v = (tid < nb) ? block_sums[tid] : 0;
    ts[tid] = v;
    __syncthreads();
    for (int off = 1; off < 256; off <<= 1) {
        int t = 0;
        if (tid >= off) t = ts[tid - off];
        __syncthreads();
        if (tid >= off) ts[tid] += t;
        __syncthreads();
    }
    if (tid < nb) block_sums[tid] = (tid > 0) ? ts[tid - 1] : 0;
    if (tid == 255) row_off[n] = ts[255];
}

__global__ __launch_bounds__(256) void scan_add(int* __restrict__ row_off,
                                                int* __restrict__ cursor,
                                                const int* __restrict__ block_sums, int n) {
    int tid = threadIdx.x;
    int off = block_sums[blockIdx.x];
    int base = blockIdx.x * SCHUNK + tid * 4;
#pragma unroll
    for (int j = 0; j < 4; ++j) {
        int i = base + j;
        if (i < n) {
            int r = row_off[i] + off;
            row_off[i] = r;
            cursor[i] = r;
        }
    }
}

__global__ __launch_bounds__(256) void fill_part(const int* __restrict__ src,
                                                 const int* __restrict__ dst, int E,
                                                 int* __restrict__ cursor,
                                                 int* __restrict__ csr_src, int npg,
                                                 int blocks_per_g, int N) {
    int g = blockIdx.x & 7;
    int bg = blockIdx.x >> 3;
    int lo = g * npg;
    int hi = min(lo + npg, N);
    for (int i = bg * 256 + threadIdx.x; i < E; i += blocks_per_g * 256) {
        int d = dst[i];
        int s = src[i];
        if (d >= lo && d < hi) {
            int p = atomicAdd(&cursor[d], 1);
            csr_src[p] = s;
        }
    }
}

// ---------------------------------------------------------------- bf16 pack
// n4 = number of float4 groups (n/4). fp32 [m] -> bf16 [m] (as uint2 per 4)
__global__ __launch_bounds__(256) void pack_bf16(const float* __restrict__ in,
                                                 uint2* __restrict__ out, int n4) {
    int i = blockIdx.x * 256 + threadIdx.x;
    if (i >= n4) return;
    float4 v = *(const float4*)&in[(size_t)i * 4];
    __hip_bfloat162 p0 = __float22bfloat162_rn(make_float2(v.x, v.y));
    __hip_bfloat162 p1 = __float22bfloat162_rn(make_float2(v.z, v.w));
    uint2 o;
    o.x = *(const uint*)&p0;
    o.y = *(const uint*)&p1;
    out[i] = o;
}

// ------------------------------------------------- mean aggregation, bf16 gather
// one wave per dst node; lane loads uint = 2 bf16 (features 2*lane, 2*lane+1)
static __device__ inline float2 unpack2(uint v) {
    float2 r;
    r.x = __uint_as_float(v << 16);
    r.y = __uint_as_float(v & 0xffff0000u);
    return r;
}

__global__ __launch_bounds__(256) void agg_bf16(const uint* __restrict__ featb,
                                                const int* __restrict__ row_off,
                                                const int* __restrict__ csr,
                                                float* __restrict__ outf, int M) {
    int node = blockIdx.x * 4 + (threadIdx.x >> 6);
    if (node >= M) return;
    int lane = threadIdx.x & 63;
    int beg = row_off[node], end = row_off[node + 1];
    float sx = 0.f, sy = 0.f;
    int i = beg;
    for (; i + 4 <= end; i += 4) {
        int s0 = csr[i], s1 = csr[i + 1], s2 = csr[i + 2], s3 = csr[i + 3];
        uint v0 = featb[(size_t)s0 * 64 + lane];
        uint v1 = featb[(size_t)s1 * 64 + lane];
        uint v2 = featb[(size_t)s2 * 64 + lane];
        uint v3 = featb[(size_t)s3 * 64 + lane];
        float2 f0 = unpack2(v0), f1 = unpack2(v1), f2 = unpack2(v2), f3 = unpack2(v3);
        sx += f0.x + f1.x + f2.x + f3.x;
        sy += f0.y + f1.y + f2.y + f3.y;
    }
    for (; i < end; ++i) {
        uint v = featb[(size_t)csr[i] * 64 + lane];
        float2 f = unpack2(v);
        sx += f.x;
        sy += f.y;
    }
    float inv = (end > beg) ? 1.0f / (float)(end - beg) : 0.0f;
    float2 o;
    o.x = sx * inv;
    o.y = sy * inv;
    ((float2*)outf)[(size_t)node * 64 + lane] = o;
}

// --------------------------------------------- fused dual GEMM: out = act(A1@W1^T + A2@W2^T + b)
// Optional bf16 mirror of out into outb (for next layer's gather).
#define BM 64
#define KB 32
__global__ __launch_bounds__(256) void gemm_dual(const float* __restrict__ A1,
                                                 const float* __restrict__ A2,
                                                 const float* __restrict__ W1,
                                                 const float* __restrict__ W2,
                                                 const float* __restrict__ bias,
                                                 float* __restrict__ out,
                                                 uint2* __restrict__ outb,   // nullable
                                                 int M, int relu) {
    __shared__ float As[KB][BM + 4];
    __shared__ float Ws[KB][128 + 4];
    int tid = threadIdx.x;
    int row0 = blockIdx.x * BM;
    int tr = tid >> 5;   // 0..7
    int tc = tid & 31;   // 0..31
    int r0 = tr * 8;
    int c0 = tc * 4;
    float acc[8][4];
#pragma unroll
    for (int i = 0; i < 8; ++i)
#pragma unroll
        for (int c = 0; c < 4; ++c) acc[i][c] = 0.f;

    for (int half = 0; half < 2; ++half) {
        const float* A = half ? A2 : A1;
        const float* W = half ? W2 : W1;
        for (int kc = 0; kc < 128; kc += KB) {
#pragma unroll
            for (int t = 0; t < 2; ++t) {
                int f = tid + t * 256;
                int r = f >> 3;
                int c4 = (f & 7) * 4;
                int gr = row0 + r;
                float4 v = make_float4(0.f, 0.f, 0.f, 0.f);
                if (gr < M) v = *(const float4*)&A[(size_t)gr * 128 + kc + c4];
                As[c4 + 0][r] = v.x;
                As[c4 + 1][r] = v.y;
                As[c4 + 2][r] = v.z;
                As[c4 + 3][r] = v.w;
            }
#pragma unroll
            for (int t = 0; t < 4; ++t) {
                int f = tid + t * 256;
                int j = f >> 3;
                int c4 = (f & 7) * 4;
                float4 v = *(const float4*)&W[(size_t)j * 128 + kc + c4];
                Ws[c4 + 0][j] = v.x;
                Ws[c4 + 1][j] = v.y;
                Ws[c4 + 2][j] = v.z;
                Ws[c4 + 3][j] = v.w;
            }
            __syncthreads();
#pragma unroll
            for (int k = 0; k < KB; ++k) {
                float4 a0 = *(const float4*)&As[k][r0];
                float4 a1 = *(const float4*)&As[k][r0 + 4];
                float4 bv = *(const float4*)&Ws[k][c0];
                float av[8] = {a0.x, a0.y, a0.z, a0.w, a1.x, a1.y, a1.z, a1.w};
                float bb[4] = {bv.x, bv.y, bv.z, bv.w};
#pragma unroll
                for (int i = 0; i < 8; ++i)
#pragma unroll
                    for (int c = 0; c < 4; ++c) acc[i][c] += av[i] * bb[c];
            }
            __syncthreads();
        }
    }
#pragma unroll
    for (int i = 0; i < 8; ++i) {
        int gr = row0 + r0 + i;
        if (gr < M) {
            float4 o;
            o.x = acc[i][0] + bias[c0 + 0];
            o.y = acc[i][1] + bias[c0 + 1];
            o.z = acc[i][2] + bias[c0 + 2];
            o.w = acc[i][3] + bias[c0 + 3];
            if (relu) {
                o.x = fmaxf(o.x, 0.f);
                o.y = fmaxf(o.y, 0.f);
                o.z = fmaxf(o.z, 0.f);
                o.w = fmaxf(o.w, 0.f);
            }
            *(float4*)&out[(size_t)gr * 128 + c0] = o;
            if (outb) {
                __hip_bfloat162 p0 = __float22bfloat162_rn(make_float2(o.x, o.y));
                __hip_bfloat162 p1 = __float22bfloat162_rn(make_float2(o.z, o.w));
                uint2 ob;
                ob.x = *(const uint*)&p0;
                ob.y = *(const uint*)&p1;
                outb[(size_t)gr * 32 + (c0 >> 2)] = ob;
            }
        }
    }
}

// ------------------------------------- layer 3 transform: zr[n][0..5]=h@Wl3^T, [6..11]=h@Wr3^T+b3
__global__ __launch_bounds__(256) void lin3_kernel(const float* __restrict__ h,
                                                   const float* __restrict__ Wl,
                                                   const float* __restrict__ Wr,
                                                   const float* __restrict__ b3,
                                                   float* __restrict__ zr, int M) {
    __shared__ float Ws[12][129];
    __shared__ float hs[16][132];
    int tid = threadIdx.x;
    for (int f = tid; f < 12 * 128; f += 256) {
        int j = f >> 7, k = f & 127;
        Ws[j][k] = (j < 6) ? Wl[j * 128 + k] : Wr[(j - 6) * 128 + k];
    }
    int node0 = blockIdx.x * 16;
#pragma unroll
    for (int t = 0; t < 2; ++t) {
        int f = tid + t * 256;
        int r = f >> 5;
        int c4 = (f & 31) * 4;
        int gn = node0 + r;
        float4 v = make_float4(0.f, 0.f, 0.f, 0.f);
        if (gn < M) v = *(const float4*)&h[(size_t)gn * 128 + c4];
        *(float4*)&hs[r][c4] = v;
    }
    __syncthreads();
    int ln = tid >> 4;
    int j = tid & 15;
    int gn = node0 + ln;
    if (j < 12 && gn < M) {
        float acc = 0.f;
#pragma unroll
        for (int k = 0; k < 128; ++k) acc += hs[ln][k] * Ws[j][k];
        if (j >= 6) acc += b3[j - 6];
        zr[(size_t)gn * 12 + j] = acc;
    }
}

// ------------------------------------------- final: out[n][j] = mean_s z[s][j] + r[n][j]
__global__ void out_kernel(const float* __restrict__ zr, const int* __restrict__ row_off,
                           const int* __restrict__ csr, float* __restrict__ out, int M) {
    int idx = blockIdx.x * blockDim.x + threadIdx.x;
    int node = idx >> 3;
    int j = idx & 7;
    if (node >= M || j >= 6) return;
    int beg = row_off[node], end = row_off[node + 1];
    float acc = 0.f;
    for (int i = beg; i < end; ++i) {
        int s = csr[i];
        acc += zr[(size_t)s * 12 + j];
    }
    float inv = (end > beg) ? 1.0f / (float)(end - beg) : 0.0f;
    out[(size_t)node * 6 + j] = acc * inv + zr[(size_t)node * 12 + 6 + j];
}

// ---------------------------------------------------------------- launch
static inline size_t align_up(size_t x, size_t a) { return (x + a - 1) & ~(a - 1); }

extern "C" void kernel_launch(void* const* d_in, const int* in_sizes, int n_in,
                              void* d_out, int out_size, void* d_ws, size_t ws_size,
                              hipStream_t stream) {
    const float* x = (const float*)d_in[0];
    const int* ei = (const int*)d_in[1];
    const float* Wl1 = (const float*)d_in[2];
    const float* Wr1 = (const float*)d_in[3];
    const float* b1 = (const float*)d_in[4];
    const float* Wl2 = (const float*)d_in[5];
    const float* Wr2 = (const float*)d_in[6];
    const float* b2 = (const float*)d_in[7];
    const float* Wl3 = (const float*)d_in[8];
    const float* Wr3 = (const float*)d_in[9];
    const float* b3 = (const float*)d_in[10];

    const int N = in_sizes[0] / 128;   // 100000
    const int E = in_sizes[1] / 2;     // 3200000
    const int* src = ei;
    const int* dst = ei + E;

    // workspace layout
    char* ws = (char*)d_ws;
    size_t off = 0;
    int* cnt = (int*)(ws + off);        off = align_up(off + (size_t)N * 4, 512);
    int* row_off = (int*)(ws + off);    off = align_up(off + (size_t)(N + 1) * 4, 512);
    int* cursor = (int*)(ws + off);     off = align_up(off + (size_t)N * 4, 512);
    int* block_sums = (int*)(ws + off); off = align_up(off + 512 * 4, 512);
    int* csr_src = (int*)(ws + off);    off = align_up(off + (size_t)E * 4, 512);
    float* aggn = (float*)(ws + off);   off = align_up(off + (size_t)N * 128 * 4, 512);
    float* h1 = (float*)(ws + off);     off = align_up(off + (size_t)N * 128 * 4, 512);
    float* h2 = (float*)(ws + off);     off = align_up(off + (size_t)N * 128 * 4, 512);
    float* zr = (float*)(ws + off);     off = align_up(off + (size_t)N * 12 * 4, 512);
    uint2* h1b = (uint2*)(ws + off);    off = align_up(off + (size_t)N * 128 * 2, 512);
    // xb aliases h2's buffer: xb live [pack, agg1], h2 live [gemm2, out] — disjoint.
    uint2* xb = (uint2*)h2;
    (void)ws_size;

    // CSR build (reused by all 3 layers), XCD-range-partitioned
    const int npg = (N + 7) / 8;
    const int blocks_per_g = 256;
    const int part_grid = 8 * blocks_per_g;
    hipMemsetAsync(cnt, 0, (size_t)N * 4, stream);
    count_part<<<part_grid, 256, 0, stream>>>(dst, E, cnt, npg, blocks_per_g, N);

    const int nscan = (N + SCHUNK - 1) / SCHUNK;
    scan_blocks<<<nscan, 256, 0, stream>>>(cnt, row_off, block_sums, N);
    scan_sums<<<1, 256, 0, stream>>>(block_sums, nscan, row_off, N);
    scan_add<<<nscan, 256, 0, stream>>>(row_off, cursor, block_sums, N);

    fill_part<<<part_grid, 256, 0, stream>>>(src, dst, E, cursor, csr_src, npg, blocks_per_g, N);

    // pack x -> bf16 (gather payload halved)
    const int n4 = N * 32;   // N*128/4
    pack_bf16<<<(n4 + 255) / 256, 256, 0, stream>>>(x, xb, n4);

    int aggGrid = (N + 3) / 4;
    int gemmGrid = (N + BM - 1) / BM;

    // layer 1: gather bf16(x), self-path fp32 x; epilogue emits bf16 h1 mirror
    agg_bf16<<<aggGrid, 256, 0, stream>>>((const uint*)xb, row_off, csr_src, aggn, N);
    gemm_dual<<<gemmGrid, 256, 0, stream>>>(aggn, x, Wl1, Wr1, b1, h1, h1b, N, 1);
    // layer 2: gather bf16(h1), self-path fp32 h1
    agg_bf16<<<aggGrid, 256, 0, stream>>>((const uint*)h1b, row_off, csr_src, aggn, N);
    gemm_dual<<<gemmGrid, 256, 0, stream>>>(aggn, h1, Wl2, Wr2, b2, h2, nullptr, N, 1);
    // layer 3: transform-then-aggregate (6-dim)
    lin3_kernel<<<(N + 15) / 16, 256, 0, stream>>>(h2, Wl3, Wr3, b3, zr, N);
    out_kernel<<<(N * 8 + 255) / 256, 256, 0, stream>>>(zr, row_off, csr_src, (float*)d_out, N);
}